// Round 6
// baseline (141.704 us; speedup 1.0000x reference)
//
#include <hip/hip_runtime.h>
#include <hip/hip_bf16.h>
#include <math.h>

// ---- problem constants (hardcoded in reference) ----
#define NMETA  4
#define NNODE  871
#define NFEAT  512
#define XDIM   (116*116)            // 13456
#define ZPLANE (NNODE*NFEAT)        // 445952
#define NCHUNK 55                   // ceil(871/16)
#define MT     55                   // M tiles of 16 (rows 864..879 padded)

// ---- workspace layout (float offsets) ----
#define WS_SPART  16                 // [220] score partials
#define WS_C1P    256                // [16*512] c1 partials
#define WS_XHP    8448               // [256*512] xh partials
#define WS_V      139520             // [871]
#define WS_CNT    140392             // [1] winner counter
#define WS_FLAGS  140400             // [55] per-mt arrival flags (int)
#define WS_EMBBP  140464             // bf16 A-frag packed emb [55+pad][64][16][8] (229376 fl)
#define WS_H2AP   369840             // bf16 A-frag packed relu(E1+c1)        (229376 fl)
#define WS_W1P    599216             // packed bf16 w1[512:1024] (131072 fl)
#define WS_W2P    730288             // packed bf16 w2           (32768 fl)

typedef short v8s __attribute__((ext_vector_type(8)));
typedef float v4f __attribute__((ext_vector_type(4)));

static __device__ __forceinline__ short f2bf(float f) {
  __hip_bfloat16 h = __float2bfloat16(f);
  return *reinterpret_cast<short*>(&h);
}

// ============ k_front: xh partials (256) | weight pack (384) | score partials (220) ============
__global__ __launch_bounds__(256) void k_front(const float* __restrict__ x,
                                               const float* __restrict__ xpw,
                                               const float* __restrict__ w1,
                                               const float* __restrict__ w2,
                                               const float* __restrict__ z,
                                               const float* __restrict__ W,
                                               const float* __restrict__ b,
                                               const float* __restrict__ q,
                                               float* __restrict__ ws,
                                               short* __restrict__ w1p,
                                               short* __restrict__ w2p) {
  const int blk = blockIdx.x;
  const int tid = threadIdx.x;
  if (blk < 256) {
    // ---- xh partials: xhp[blk][f] = sum_{d in blk's 53 rows} x[d]*xp_w[d,f]
    const int f4 = tid & 127;
    const int rp = tid >> 7;
    const int d0 = blk * 53;
    const int rows = min(53, XDIM - d0);   // may be <=0 for last blocks -> zero partial
    __shared__ float xs[53];
    if (tid < rows) xs[tid] = x[d0 + tid];
    __syncthreads();
    float4 acc = {0.f, 0.f, 0.f, 0.f};
    const float4* xp4 = (const float4*)xpw;
#pragma unroll 4
    for (int r = rp; r < rows; r += 2) {
      const float xv = xs[r];
      const float4 w = xp4[(size_t)(d0 + r) * 128 + f4];
      acc.x += xv * w.x; acc.y += xv * w.y; acc.z += xv * w.z; acc.w += xv * w.w;
    }
    __shared__ float4 red4[128];
    if (rp) red4[f4] = acc;
    __syncthreads();
    if (!rp) {
      float4 o = red4[f4];
      o.x += acc.x; o.y += acc.y; o.z += acc.z; o.w += acc.w;
      ((float4*)(ws + WS_XHP + (size_t)blk * NFEAT))[f4] = o;
    }
  } else if (blk < 640) {
    // ---- pack w1[512:1024] and w2 into MFMA B-fragment order (bf16); 4 elems/thread
    const int base = (blk - 256) * 256 + tid;
#pragma unroll
    for (int it = 0; it < 4; ++it) {
      int t = base + it * 98304;
      if (t < 262144) {
        int j = t & 7; int r = t >> 3;
        int n15 = r & 15; r >>= 4;
        int quad = r & 3; r >>= 2;
        int nt = r & 31; int kb = r >> 5;       // NT=32
        int k = kb * 32 + quad * 8 + j;
        int n = nt * 16 + n15;
        w1p[t] = f2bf(w1[(size_t)(512 + k) * 512 + n]);
      } else {
        int o = t - 262144;
        int j = o & 7; int r = o >> 3;
        int n15 = r & 15; r >>= 4;
        int quad = r & 3; r >>= 2;
        int nt = r & 15; int kb = r >> 4;       // NT=16
        int k = kb * 32 + quad * 8 + j;
        int n = nt * 16 + n15;
        w2p[o] = f2bf(w2[(size_t)k * 256 + n]);
      }
    }
  } else {
    // ---- score partials (plain store)
    const int sblk = blk - 640;
    const int p = sblk / NCHUNK;
    const int chunk = sblk % NCHUNK;
    const int i0 = chunk * 16;
    const int i1 = min(i0 + 16, NNODE);
    const int f4 = tid & 127;
    const int ip = tid >> 7;
    float local = 0.f;
    for (int i = i0 + ip; i < i1; i += 2) {
      const float wi = W[i];
      const float bi = b[i];
      const float4 zr = ((const float4*)(z + ((size_t)p * NNODE + i) * NFEAT))[f4];
      const float4 qr = ((const float4*)(q + (size_t)i * NFEAT))[f4];
      local += tanhf(wi * zr.x + bi) * qr.x + tanhf(wi * zr.y + bi) * qr.y
             + tanhf(wi * zr.z + bi) * qr.z + tanhf(wi * zr.w + bi) * qr.w;
    }
    __shared__ float red[256];
    red[tid] = local;
    __syncthreads();
    for (int s = 128; s > 0; s >>= 1) {
      if (tid < s) red[tid] += red[tid + s];
      __syncthreads();
    }
    if (tid == 0) ws[WS_SPART + sblk] = red[0];
  }
}

// ============ k_prep2: emb (220) | c1 partials (16) | zero v/cnt/flags (1) ============
__global__ __launch_bounds__(256) void k_prep2(const float* __restrict__ z,
                                               const float* __restrict__ xpb,
                                               const float* __restrict__ w1,
                                               const float* __restrict__ b1,
                                               float* __restrict__ ws,
                                               float* __restrict__ out,
                                               short* __restrict__ embp) {
  const int tid = threadIdx.x;
  if (blockIdx.x < 220) {
    // ---- emb: 4 rows per block; coef recomputed per block from score partials
    __shared__ float sp[220];
    if (tid < 220) sp[tid] = ws[WS_SPART + tid];
    __syncthreads();
    float sv[NMETA], sum = 0.f;
#pragma unroll
    for (int p = 0; p < NMETA; ++p) {
      float s = 0.f;
      for (int c = 0; c < NCHUNK; ++c) s += sp[p * NCHUNK + c];
      sv[p] = s / (float)NNODE;
      sum += sv[p];
    }
    float m = -1e30f;
#pragma unroll
    for (int p = 0; p < NMETA; ++p) { sv[p] = sv[p] / sum; m = fmaxf(m, sv[p]); }
    float es = 0.f;
#pragma unroll
    for (int p = 0; p < NMETA; ++p) { sv[p] = expf(sv[p] - m); es += sv[p]; }
    const float c0 = 1.f + sv[0] / es, c1c = 1.f + sv[1] / es;
    const float c2 = 1.f + sv[2] / es, c3 = 1.f + sv[3] / es;

    const int mt = blockIdx.x >> 2;
    const int rl = (blockIdx.x & 3) * 4 + (tid >> 6);   // row in tile 0..15
    const int gr = mt * 16 + rl;
    const int oc = tid & 63;                            // k-octet
    v8s h;
    if (gr < NNODE) {
      const float4* z4 = (const float4*)z;
      const int zi = gr * 128 + oc * 2;
      float4 a0 = z4[zi],               a1 = z4[zi + 1];
      float4 b0 = z4[NNODE*128 + zi],   b1v = z4[NNODE*128 + zi + 1];
      float4 d0 = z4[2*NNODE*128 + zi], d1 = z4[2*NNODE*128 + zi + 1];
      float4 e0 = z4[3*NNODE*128 + zi], e1 = z4[3*NNODE*128 + zi + 1];
      float4 r0v, r1v;
      r0v.x = c0*a0.x + c1c*b0.x + c2*d0.x + c3*e0.x;
      r0v.y = c0*a0.y + c1c*b0.y + c2*d0.y + c3*e0.y;
      r0v.z = c0*a0.z + c1c*b0.z + c2*d0.z + c3*e0.z;
      r0v.w = c0*a0.w + c1c*b0.w + c2*d0.w + c3*e0.w;
      r1v.x = c0*a1.x + c1c*b1v.x + c2*d1.x + c3*e1.x;
      r1v.y = c0*a1.y + c1c*b1v.y + c2*d1.y + c3*e1.y;
      r1v.z = c0*a1.z + c1c*b1v.z + c2*d1.z + c3*e1.z;
      r1v.w = c0*a1.w + c1c*b1v.w + c2*d1.w + c3*e1.w;
      ((float4*)out)[zi] = r0v;
      ((float4*)out)[zi + 1] = r1v;
      h[0] = f2bf(r0v.x); h[1] = f2bf(r0v.y); h[2] = f2bf(r0v.z); h[3] = f2bf(r0v.w);
      h[4] = f2bf(r1v.x); h[5] = f2bf(r1v.y); h[6] = f2bf(r1v.z); h[7] = f2bf(r1v.w);
    } else {
      h = (v8s){0,0,0,0,0,0,0,0};
    }
    *(v8s*)(embp + ((size_t)(mt * 64 + oc) * 16 + rl) * 8) = h;
  } else if (blockIdx.x < 236) {
    // ---- c1 partials: slice [bk*32, bk*32+32), reduce 256 xh partials then @w1a
    const int bk = blockIdx.x - 220;
    __shared__ float xs[32];
    {
      const int f = tid & 31;
      const int pg = tid >> 5;
      float s = 0.f;
#pragma unroll 4
      for (int p = pg; p < 256; p += 8)
        s += ws[WS_XHP + (size_t)p * NFEAT + bk * 32 + f];
      __shared__ float red[256];
      red[tid] = s;
      __syncthreads();
      if (tid < 32) {
        float t2 = 0.f;
#pragma unroll
        for (int g = 0; g < 8; ++g) t2 += red[g * 32 + tid];
        xs[tid] = t2 + xpb[bk * 32 + tid];
      }
      __syncthreads();
    }
    const int j4 = tid & 127;
    const int fp = tid >> 7;
    float4 acc = {0.f, 0.f, 0.f, 0.f};
    const float4* w14 = (const float4*)w1;
#pragma unroll
    for (int ff = 0; ff < 16; ++ff) {
      const int f = bk * 32 + fp * 16 + ff;
      const float xv = xs[fp * 16 + ff];
      const float4 w = w14[(size_t)f * 128 + j4];
      acc.x += xv * w.x; acc.y += xv * w.y; acc.z += xv * w.z; acc.w += xv * w.w;
    }
    __shared__ float4 red2[128];
    if (fp) red2[j4] = acc;
    __syncthreads();
    if (!fp) {
      float4 o = red2[j4];
      o.x += acc.x; o.y += acc.y; o.z += acc.z; o.w += acc.w;
      if (bk == 0) {
        o.x += b1[j4 * 4 + 0]; o.y += b1[j4 * 4 + 1];
        o.z += b1[j4 * 4 + 2]; o.w += b1[j4 * 4 + 3];
      }
      ((float4*)(ws + WS_C1P + (size_t)bk * NFEAT))[j4] = o;
    }
  } else {
    // ---- zero v, counter, flags
    for (int i = tid; i < NNODE; i += 256) ws[WS_V + i] = 0.f;
    if (tid == 0) *(unsigned int*)&ws[WS_CNT] = 0u;
    if (tid < MT) ((unsigned int*)&ws[WS_FLAGS])[tid] = 0u;
  }
}

// ============ k_gemmAll: E1 half-tiles (110 blocks); last-arriver does H2+rowdot; ============
// ============ 55th winner does the final loss                                     ============
__global__ __launch_bounds__(256) void k_gemmAll(float* __restrict__ ws,
                                                 float* __restrict__ out,
                                                 const short* __restrict__ embp,
                                                 short* __restrict__ h2ap,
                                                 const short* __restrict__ w1p,
                                                 const short* __restrict__ w2p,
                                                 const float* __restrict__ b2,
                                                 const float* __restrict__ w3,
                                                 const float* __restrict__ b3) {
  const int tid = threadIdx.x;
  const int mt = blockIdx.x >> 1;
  const int nh = blockIdx.x & 1;            // column half: cols nh*256..nh*256+255
  const int lane = tid & 63, w = tid >> 6;
  const int n15 = lane & 15, quad = lane >> 4;

  // c1 for this half into LDS
  __shared__ float cs[256];
  {
    float a = 0.f;
#pragma unroll
    for (int k = 0; k < 16; ++k) a += ws[WS_C1P + k * 512 + nh * 256 + tid];
    cs[tid] = a;
  }
  __syncthreads();

  // ---- E1 phase: wave w covers cols nh*256 + w*64 .. +63 (4 n-tiles)
  v4f e[4];
#pragma unroll
  for (int ct = 0; ct < 4; ++ct) e[ct] = (v4f){0.f, 0.f, 0.f, 0.f};
#pragma unroll
  for (int kb = 0; kb < 16; ++kb) {
    const int koct = kb * 4 + quad;
    v8s a = *(const v8s*)(embp + ((size_t)(mt * 64 + koct) * 16 + n15) * 8);
    const short* B = w1p + kb * 16384 + (nh * 16 + w * 4) * 512 + quad * 128 + n15 * 8;
#pragma unroll
    for (int ct = 0; ct < 4; ++ct) {
      v8s bb = *(const v8s*)(B + ct * 512);
      e[ct] = __builtin_amdgcn_mfma_f32_16x16x32_bf16(a, bb, e[ct], 0, 0, 0);
    }
  }
  // epilogue: relu(E1+c1) -> bf16 -> global A-frag packed
#pragma unroll
  for (int ct = 0; ct < 4; ++ct) {
    const int cl = w * 64 + ct * 16 + n15;          // 0..255
    const int col = nh * 256 + cl;
    const int koct = col >> 3, j = col & 7;
#pragma unroll
    for (int r = 0; r < 4; ++r) {
      const int m = quad * 4 + r;
      h2ap[((size_t)(mt * 64 + koct) * 16 + m) * 8 + j] = f2bf(fmaxf(e[ct][r] + cs[cl], 0.f));
    }
  }

  // ---- last-arriver per mt: winner does H2 + rowdot
  __shared__ int win;
  __syncthreads();
  if (tid == 0) {
    __threadfence();
    unsigned old = atomicAdd((unsigned int*)&ws[WS_FLAGS] + mt, 1u);
    win = (old == 1u) ? 1 : 0;
  }
  __syncthreads();
  if (win) {
    __threadfence();                                // acquire: see sibling's h2ap stores
    v4f g[4];
#pragma unroll
    for (int ct = 0; ct < 4; ++ct) g[ct] = (v4f){0.f, 0.f, 0.f, 0.f};
#pragma unroll
    for (int kb = 0; kb < 16; ++kb) {
      const int koct = kb * 4 + quad;
      v8s a = *(const v8s*)(h2ap + ((size_t)(mt * 64 + koct) * 16 + n15) * 8);
      const short* B = w2p + kb * 8192 + (w * 4) * 512 + quad * 128 + n15 * 8;
#pragma unroll
      for (int ct = 0; ct < 4; ++ct) {
        v8s bb = *(const v8s*)(B + ct * 512);
        g[ct] = __builtin_amdgcn_mfma_f32_16x16x32_bf16(a, bb, g[ct], 0, 0, 0);
      }
    }
#pragma unroll
    for (int r = 0; r < 4; ++r) {
      float s = 0.f;
#pragma unroll
      for (int ct = 0; ct < 4; ++ct) {
        const int col = w * 64 + ct * 16 + n15;
        s += fmaxf(g[ct][r] + b2[col], 0.f) * w3[col];
      }
      s += __shfl_xor(s, 1);
      s += __shfl_xor(s, 2);
      s += __shfl_xor(s, 4);
      s += __shfl_xor(s, 8);
      const int grow = mt * 16 + quad * 4 + r;
      if (n15 == 0 && grow < NNODE) atomicAdd(&ws[WS_V + grow], s);
    }

    // ---- 55th winner computes the loss
    __shared__ int last;
    __syncthreads();
    if (tid == 0) {
      __threadfence();
      unsigned old = atomicAdd((unsigned int*)&ws[WS_CNT], 1u);
      last = (old == MT - 1) ? 1 : 0;
    }
    __syncthreads();
    if (last) {
      __shared__ float rf0[256], rf1[256];
      const float bias = b3[0];
      float s0 = 0.f, s1 = 0.f;
      for (int i = tid; i < NNODE; i += 256) {
        float xv = __hip_atomic_load(&ws[WS_V + i], __ATOMIC_RELAXED,
                                     __HIP_MEMORY_SCOPE_AGENT) + bias;
        s0 += xv;
        s1 += expf(xv);
      }
      rf0[tid] = s0; rf1[tid] = s1;
      __syncthreads();
      for (int s = 128; s > 0; s >>= 1) {
        if (tid < s) { rf0[tid] += rf0[tid + s]; rf1[tid] += rf1[tid + s]; }
        __syncthreads();
      }
      if (tid == 0) {
        float m0 = rf0[0] / (float)NNODE;
        float m1 = rf1[0] / (float)NNODE;
        float mi = m0 - logf(m1 + 1e-8f);
        out[ZPLANE] = fmaxf(mi, 0.f) + 0.1f;  // sum(softmax)==1 -> gamma term = 0.1
      }
    }
  }
}

extern "C" void kernel_launch(void* const* d_in, const int* in_sizes, int n_in,
                              void* d_out, int out_size, void* d_ws, size_t ws_size,
                              hipStream_t stream) {
  const float* z   = (const float*)d_in[0];
  const float* x   = (const float*)d_in[1];
  const float* W   = (const float*)d_in[2];
  const float* b   = (const float*)d_in[3];
  const float* q   = (const float*)d_in[4];
  const float* xpw = (const float*)d_in[5];
  const float* xpb = (const float*)d_in[6];
  const float* w1  = (const float*)d_in[7];
  const float* b1  = (const float*)d_in[8];
  const float* w2  = (const float*)d_in[9];
  const float* b2  = (const float*)d_in[10];
  const float* w3  = (const float*)d_in[11];
  const float* b3  = (const float*)d_in[12];
  // d_in[13] (perm) unused: xh identical per row => permutation invariant under mean(exp(.)).
  float* out = (float*)d_out;
  float* ws  = (float*)d_ws;

  short* embp = (short*)(ws + WS_EMBBP);
  short* h2ap = (short*)(ws + WS_H2AP);
  short* w1p  = (short*)(ws + WS_W1P);
  short* w2p  = (short*)(ws + WS_W2P);

  k_front<<<860, 256, 0, stream>>>(x, xpw, w1, w2, z, W, b, q, ws, w1p, w2p);
  k_prep2<<<237, 256, 0, stream>>>(z, xpb, w1, b1, ws, out, embp);
  k_gemmAll<<<110, 256, 0, stream>>>(ws, out, embp, h2ap, w1p, w2p, b2, w3, b3);
}

// Round 7
// 127.832 us; speedup vs baseline: 1.1085x; 1.1085x over previous
//
#include <hip/hip_runtime.h>
#include <hip/hip_bf16.h>
#include <math.h>

// ---- problem constants (hardcoded in reference) ----
#define NMETA  4
#define NNODE  871
#define NFEAT  512
#define XDIM   (116*116)            // 13456
#define ZPLANE (NNODE*NFEAT)        // 445952
#define NCHUNK 55                   // ceil(871/16)
#define MT     55                   // M tiles of 16 (rows 871..879 padded)

// ---- workspace layout (float offsets) ----
#define WS_COEF   8                  // [4]  (1+attn)
#define WS_CNT    12                 // [1]  block-completion counter
#define WS_SPART  16                 // [220] score partials (p*55+chunk)
#define WS_C1P    256                // [16*512] c1 partials
#define WS_XHP    8448               // [128*512] xh partials
#define WS_V      73984              // [871]
#define WS_W1P    74856              // packed bf16 w1[512:1024] (131072 floats)
#define WS_W2P    205928             // packed bf16 w2 (32768 floats)

typedef short v8s __attribute__((ext_vector_type(8)));
typedef float v4f __attribute__((ext_vector_type(4)));

static __device__ __forceinline__ short f2bf(float f) {
  __hip_bfloat16 h = __float2bfloat16(f);
  return *reinterpret_cast<short*>(&h);
}

// ============ k_front: xh partials (128) | weight pack (384) | score partials (220) ============
__global__ __launch_bounds__(256) void k_front(const float* __restrict__ x,
                                               const float* __restrict__ xpw,
                                               const float* __restrict__ w1,
                                               const float* __restrict__ w2,
                                               const float* __restrict__ z,
                                               const float* __restrict__ W,
                                               const float* __restrict__ b,
                                               const float* __restrict__ q,
                                               float* __restrict__ ws,
                                               short* __restrict__ w1p,
                                               short* __restrict__ w2p) {
  const int blk = blockIdx.x;
  const int tid = threadIdx.x;
  if (blk < 128) {
    // ---- xh partials: xhp[blk][f] = sum_{d in blk} x[d]*xp_w[d,f]
    const int f4 = tid & 127;
    const int rp = tid >> 7;
    const int d0 = blk * 106;
    const int rows = min(106, XDIM - d0);
    __shared__ float xs[106];
    if (tid < rows) xs[tid] = x[d0 + tid];
    __syncthreads();
    float4 acc = {0.f, 0.f, 0.f, 0.f};
    const float4* xp4 = (const float4*)xpw;
#pragma unroll 4
    for (int r = rp; r < rows; r += 2) {
      const float xv = xs[r];
      const float4 w = xp4[(size_t)(d0 + r) * 128 + f4];
      acc.x += xv * w.x; acc.y += xv * w.y; acc.z += xv * w.z; acc.w += xv * w.w;
    }
    __shared__ float4 red4[128];
    if (rp) red4[f4] = acc;
    __syncthreads();
    if (!rp) {
      float4 o = red4[f4];
      o.x += acc.x; o.y += acc.y; o.z += acc.z; o.w += acc.w;
      ((float4*)(ws + WS_XHP + (size_t)blk * NFEAT))[f4] = o;
    }
  } else if (blk < 512) {
    // ---- pack w1[512:1024] and w2 into MFMA B-fragment order (bf16); 4 elems/thread
    const int base = (blk - 128) * 256 + tid;
#pragma unroll
    for (int it = 0; it < 4; ++it) {
      int t = base + it * 98304;
      if (t < 262144) {
        int j = t & 7; int r = t >> 3;
        int n15 = r & 15; r >>= 4;
        int quad = r & 3; r >>= 2;
        int nt = r & 31; int kb = r >> 5;       // NT=32
        int k = kb * 32 + quad * 8 + j;
        int n = nt * 16 + n15;
        w1p[t] = f2bf(w1[(size_t)(512 + k) * 512 + n]);
      } else {
        int o = t - 262144;
        int j = o & 7; int r = o >> 3;
        int n15 = r & 15; r >>= 4;
        int quad = r & 3; r >>= 2;
        int nt = r & 15; int kb = r >> 4;       // NT=16
        int k = kb * 32 + quad * 8 + j;
        int n = nt * 16 + n15;
        w2p[o] = f2bf(w2[(size_t)k * 256 + n]);
      }
    }
  } else {
    // ---- score partials: spart[p*55+chunk] (plain store, no atomics)
    const int sblk = blk - 512;
    const int p = sblk / NCHUNK;
    const int chunk = sblk % NCHUNK;
    const int i0 = chunk * 16;
    const int i1 = min(i0 + 16, NNODE);
    const int f4 = tid & 127;
    const int ip = tid >> 7;
    float local = 0.f;
    for (int i = i0 + ip; i < i1; i += 2) {
      const float wi = W[i];
      const float bi = b[i];
      const float4 zr = ((const float4*)(z + ((size_t)p * NNODE + i) * NFEAT))[f4];
      const float4 qr = ((const float4*)(q + (size_t)i * NFEAT))[f4];
      local += tanhf(wi * zr.x + bi) * qr.x + tanhf(wi * zr.y + bi) * qr.y
             + tanhf(wi * zr.z + bi) * qr.z + tanhf(wi * zr.w + bi) * qr.w;
    }
    __shared__ float red[256];
    red[tid] = local;
    __syncthreads();
    for (int s = 128; s > 0; s >>= 1) {
      if (tid < s) red[tid] += red[tid + s];
      __syncthreads();
    }
    if (tid == 0) ws[WS_SPART + sblk] = red[0];
  }
}

// ============ k_prep: c1 partials (16 blocks) | coef + zero v/counter (1 block) ============
__global__ __launch_bounds__(256) void k_prep(const float* __restrict__ xpb,
                                              const float* __restrict__ w1,
                                              const float* __restrict__ b1,
                                              float* __restrict__ ws) {
  const int tid = threadIdx.x;
  if (blockIdx.x < 16) {
    const int bk = blockIdx.x;                // f-slice [bk*32, bk*32+32)
    __shared__ float xs[32];
    {
      const int f = tid & 31;
      const int pg = tid >> 5;
      float s = 0.f;
#pragma unroll 4
      for (int p = pg; p < 128; p += 8)
        s += ws[WS_XHP + (size_t)p * NFEAT + bk * 32 + f];
      __shared__ float red[256];
      red[tid] = s;
      __syncthreads();
      if (tid < 32) {
        float t2 = 0.f;
#pragma unroll
        for (int g = 0; g < 8; ++g) t2 += red[g * 32 + tid];
        xs[tid] = t2 + xpb[bk * 32 + tid];
      }
      __syncthreads();
    }
    const int j4 = tid & 127;
    const int fp = tid >> 7;
    float4 acc = {0.f, 0.f, 0.f, 0.f};
    const float4* w14 = (const float4*)w1;
#pragma unroll
    for (int ff = 0; ff < 16; ++ff) {
      const int f = bk * 32 + fp * 16 + ff;
      const float xv = xs[fp * 16 + ff];
      const float4 w = w14[(size_t)f * 128 + j4];
      acc.x += xv * w.x; acc.y += xv * w.y; acc.z += xv * w.z; acc.w += xv * w.w;
    }
    __shared__ float4 red2[128];
    if (fp) red2[j4] = acc;
    __syncthreads();
    if (!fp) {
      float4 o = red2[j4];
      o.x += acc.x; o.y += acc.y; o.z += acc.z; o.w += acc.w;
      if (bk == 0) {
        o.x += b1[j4 * 4 + 0]; o.y += b1[j4 * 4 + 1];
        o.z += b1[j4 * 4 + 2]; o.w += b1[j4 * 4 + 3];
      }
      ((float4*)(ws + WS_C1P + (size_t)bk * NFEAT))[j4] = o;
    }
  } else {
    // coef from score partials; zero v and counter
    __shared__ float sp[220];
    if (tid < 220) sp[tid] = ws[WS_SPART + tid];
    __syncthreads();
    if (tid == 0) {
      float sv[NMETA], sum = 0.f;
#pragma unroll
      for (int p = 0; p < NMETA; ++p) {
        float s = 0.f;
        for (int c = 0; c < NCHUNK; ++c) s += sp[p * NCHUNK + c];
        sv[p] = s / (float)NNODE;
        sum += sv[p];
      }
      float m = -1e30f;
#pragma unroll
      for (int p = 0; p < NMETA; ++p) { sv[p] = sv[p] / sum; m = fmaxf(m, sv[p]); }
      float es = 0.f;
#pragma unroll
      for (int p = 0; p < NMETA; ++p) { sv[p] = expf(sv[p] - m); es += sv[p]; }
#pragma unroll
      for (int p = 0; p < NMETA; ++p) ws[WS_COEF + p] = 1.f + sv[p] / es;
      *(unsigned int*)&ws[WS_CNT] = 0u;
    }
    for (int i = tid; i < NNODE; i += 256) ws[WS_V + i] = 0.f;
  }
}

// ============ k_fused (512 thr): emb -> E1 -> relu+c1 -> H2 -> rowdot -> (last) loss ============
// one block per 16-row M-tile; 8 waves; LDS A-frag slot: (koct*16 + (m ^ (koct&15)))
__global__ __launch_bounds__(512) void k_fused(const float* __restrict__ z,
                                               float* __restrict__ ws,
                                               float* __restrict__ out,
                                               const short* __restrict__ w1p,
                                               const short* __restrict__ w2p,
                                               const float* __restrict__ b2,
                                               const float* __restrict__ w3,
                                               const float* __restrict__ b3) {
  __shared__ __align__(16) short embs[8192];   // [64 koct][16 m][8], swizzled
  __shared__ __align__(16) short h2a[8192];
  __shared__ float cs[512];
  __shared__ float rf0[512], rf1[512];
  const int tid = threadIdx.x;
  const int r0 = blockIdx.x * 16;

  // c1 = sum of 16 partials (one element per thread)
  {
    float a0 = 0.f;
#pragma unroll
    for (int k = 0; k < 16; ++k) a0 += ws[WS_C1P + k * 512 + tid];
    cs[tid] = a0;
  }
  const float c0 = ws[WS_COEF + 0], c1c = ws[WS_COEF + 1];
  const float c2 = ws[WS_COEF + 2], c3 = ws[WS_COEF + 3];

  // emb for this tile's 16 rows: fp32 -> d_out, bf16 -> embs (A-fragment layout)
  const int oc = tid & 63;                    // k-octet 0..63
  const float4* z4 = (const float4*)z;
  float4* out4 = (float4*)out;
#pragma unroll
  for (int t = 0; t < 2; ++t) {
    const int row = (tid >> 6) + 8 * t;       // 0..15
    const int gr = r0 + row;
    const int slot = oc * 16 + (row ^ (oc & 15));
    v8s h;
    if (gr < NNODE) {
      const int zi = gr * 128 + oc * 2;
      float4 a0 = z4[zi],               a1 = z4[zi + 1];
      float4 b0 = z4[NNODE*128 + zi],   b1 = z4[NNODE*128 + zi + 1];
      float4 d0 = z4[2*NNODE*128 + zi], d1 = z4[2*NNODE*128 + zi + 1];
      float4 e0 = z4[3*NNODE*128 + zi], e1 = z4[3*NNODE*128 + zi + 1];
      float4 r0v, r1v;
      r0v.x = c0*a0.x + c1c*b0.x + c2*d0.x + c3*e0.x;
      r0v.y = c0*a0.y + c1c*b0.y + c2*d0.y + c3*e0.y;
      r0v.z = c0*a0.z + c1c*b0.z + c2*d0.z + c3*e0.z;
      r0v.w = c0*a0.w + c1c*b0.w + c2*d0.w + c3*e0.w;
      r1v.x = c0*a1.x + c1c*b1.x + c2*d1.x + c3*e1.x;
      r1v.y = c0*a1.y + c1c*b1.y + c2*d1.y + c3*e1.y;
      r1v.z = c0*a1.z + c1c*b1.z + c2*d1.z + c3*e1.z;
      r1v.w = c0*a1.w + c1c*b1.w + c2*d1.w + c3*e1.w;
      out4[zi] = r0v;
      out4[zi + 1] = r1v;
      h[0] = f2bf(r0v.x); h[1] = f2bf(r0v.y); h[2] = f2bf(r0v.z); h[3] = f2bf(r0v.w);
      h[4] = f2bf(r1v.x); h[5] = f2bf(r1v.y); h[6] = f2bf(r1v.z); h[7] = f2bf(r1v.w);
    } else {
      h = (v8s){0,0,0,0,0,0,0,0};
    }
    *(v8s*)(embs + slot * 8) = h;
  }
  __syncthreads();

  // E1 phase: wave w (0..7) handles cols w*64..w*64+63 (4 n-tiles)
  const int lane = tid & 63, w = tid >> 6;
  const int n15 = lane & 15, quad = lane >> 4;
  v4f e[4];
#pragma unroll
  for (int ct = 0; ct < 4; ++ct) e[ct] = (v4f){0.f, 0.f, 0.f, 0.f};
#pragma unroll
  for (int kb = 0; kb < 16; ++kb) {
    const int koct = kb * 4 + quad;
    v8s a = *(const v8s*)(embs + (koct * 16 + (n15 ^ (koct & 15))) * 8);
    const short* B = w1p + kb * 16384 + w * 2048 + quad * 128 + n15 * 8;
#pragma unroll
    for (int ct = 0; ct < 4; ++ct) {
      v8s bb = *(const v8s*)(B + ct * 512);
      e[ct] = __builtin_amdgcn_mfma_f32_16x16x32_bf16(a, bb, e[ct], 0, 0, 0);
    }
  }
  // relu(E1+c1) -> bf16 -> h2a (A-fragment layout for H2)
#pragma unroll
  for (int ct = 0; ct < 4; ++ct) {
    const int col = w * 64 + ct * 16 + n15;
    const int koct = col >> 3, j = col & 7;
#pragma unroll
    for (int r = 0; r < 4; ++r) {
      const int m = quad * 4 + r;
      h2a[(koct * 16 + (m ^ (koct & 15))) * 8 + j] = f2bf(fmaxf(e[ct][r] + cs[col], 0.f));
    }
  }
  __syncthreads();

  // H2 phase: wave w handles cols w*32..w*32+31 (2 n-tiles); fused rowdot
  v4f g[2];
#pragma unroll
  for (int ct = 0; ct < 2; ++ct) g[ct] = (v4f){0.f, 0.f, 0.f, 0.f};
#pragma unroll
  for (int kb = 0; kb < 16; ++kb) {
    const int koct = kb * 4 + quad;
    v8s a = *(const v8s*)(h2a + (koct * 16 + (n15 ^ (koct & 15))) * 8);
    const short* B = w2p + kb * 8192 + w * 1024 + quad * 128 + n15 * 8;
#pragma unroll
    for (int ct = 0; ct < 2; ++ct) {
      v8s bb = *(const v8s*)(B + ct * 512);
      g[ct] = __builtin_amdgcn_mfma_f32_16x16x32_bf16(a, bb, g[ct], 0, 0, 0);
    }
  }
#pragma unroll
  for (int r = 0; r < 4; ++r) {
    float s = 0.f;
#pragma unroll
    for (int ct = 0; ct < 2; ++ct) {
      const int col = w * 32 + ct * 16 + n15;
      s += fmaxf(g[ct][r] + b2[col], 0.f) * w3[col];
    }
    s += __shfl_xor(s, 1);
    s += __shfl_xor(s, 2);
    s += __shfl_xor(s, 4);
    s += __shfl_xor(s, 8);
    const int grow = r0 + quad * 4 + r;
    if (n15 == 0 && grow < NNODE) atomicAdd(&ws[WS_V + grow], s);
  }

  // last-block final loss
  __shared__ unsigned last;
  __syncthreads();
  if (tid == 0) {
    __threadfence();
    unsigned old = atomicAdd((unsigned int*)&ws[WS_CNT], 1u);
    last = (old == MT - 1) ? 1u : 0u;
  }
  __syncthreads();
  if (last) {
    const float bias = b3[0];
    float s0 = 0.f, s1 = 0.f;
    for (int i = tid; i < NNODE; i += 512) {
      float xv = __hip_atomic_load(&ws[WS_V + i], __ATOMIC_RELAXED,
                                   __HIP_MEMORY_SCOPE_AGENT) + bias;
      s0 += xv;
      s1 += expf(xv);
    }
    rf0[tid] = s0; rf1[tid] = s1;
    __syncthreads();
    for (int s = 256; s > 0; s >>= 1) {
      if (tid < s) { rf0[tid] += rf0[tid + s]; rf1[tid] += rf1[tid + s]; }
      __syncthreads();
    }
    if (tid == 0) {
      float m0 = rf0[0] / (float)NNODE;
      float m1 = rf1[0] / (float)NNODE;
      float mi = m0 - logf(m1 + 1e-8f);
      out[ZPLANE] = fmaxf(mi, 0.f) + 0.1f;  // sum(softmax)==1 exactly -> gamma term = 0.1
    }
  }
}

extern "C" void kernel_launch(void* const* d_in, const int* in_sizes, int n_in,
                              void* d_out, int out_size, void* d_ws, size_t ws_size,
                              hipStream_t stream) {
  const float* z   = (const float*)d_in[0];
  const float* x   = (const float*)d_in[1];
  const float* W   = (const float*)d_in[2];
  const float* b   = (const float*)d_in[3];
  const float* q   = (const float*)d_in[4];
  const float* xpw = (const float*)d_in[5];
  const float* xpb = (const float*)d_in[6];
  const float* w1  = (const float*)d_in[7];
  const float* b1  = (const float*)d_in[8];
  const float* w2  = (const float*)d_in[9];
  const float* b2  = (const float*)d_in[10];
  const float* w3  = (const float*)d_in[11];
  const float* b3  = (const float*)d_in[12];
  // d_in[13] (perm) unused: xh identical per row => permutation invariant under mean(exp(.)).
  float* out = (float*)d_out;
  float* ws  = (float*)d_ws;

  short* w1p = (short*)(ws + WS_W1P);
  short* w2p = (short*)(ws + WS_W2P);

  k_front<<<732, 256, 0, stream>>>(x, xpw, w1, w2, z, W, b, q, ws, w1p, w2p);
  k_prep<<<17, 256, 0, stream>>>(xpb, w1, b1, ws);
  k_fused<<<MT, 512, 0, stream>>>(z, ws, out, w1p, w2p, b2, w3, b3);
}